// Round 1
// baseline (2697.156 us; speedup 1.0000x reference)
//
#include <hip/hip_runtime.h>
#include <hip/hip_cooperative_groups.h>

namespace cg = cooperative_groups;

// ShootingBlock: only the u-trajectory is observable (traj records y[2K:];
// du = relu(u)@theta^T + bias is self-contained; Mbar/Mbar_b are identity).
//
// R7 (from R6's 590 us): fuse all 20 feval launches into ONE cooperative
// kernel with grid.sync() between RK4 stages. Each block owns a fixed
// (m0,n0) 64x64 tile across the whole integration, so u and the RK4
// accumulator live in REGISTERS (16 f32 each/thread) -> removes the
// acc read/write (48 MB/step) and repeated uStd reads (32 MB/step) plus
// 16 launch drain/ramp boundaries per sweep. Main-loop structure (swizzled
// LDS, 6-product split-3 bf16 MFMA, double-buffered glds16) unchanged.
// Numerics identical to R6. Fallback to the 20-launch path if cooperative
// launch is unavailable.

namespace {

constexpr int KP = 1024;
constexpr int D  = 512;
constexpr int M  = 4096;

typedef __attribute__((ext_vector_type(8))) short short8;   // 8 bf16 (4 VGPRs)
typedef __attribute__((ext_vector_type(4))) float f32x4;

__device__ __forceinline__ unsigned short f2bf(float f) {  // RNE
  unsigned int u = __float_as_uint(f);
  u += 0x7FFF + ((u >> 16) & 1);
  return (unsigned short)(u >> 16);
}
__device__ __forceinline__ float bf2f(unsigned short h) {
  return __uint_as_float(((unsigned int)h) << 16);
}

__device__ __forceinline__ void glds16(const unsigned short* g, unsigned short* l) {
  __builtin_amdgcn_global_load_lds(
      (__attribute__((address_space(1))) const void*)g,
      (__attribute__((address_space(3))) void*)l, 16, 0, 0);
}

// ---------------------------------------------------------------------------
// part[z][d][e] = sum_{k in chunk z} ps[k][d] * relu(xs[k][e])   (std layout)
// ---------------------------------------------------------------------------
constexpr int KSPLIT = 8;

__global__ __launch_bounds__(256) void theta_partial_kernel(
    const float* __restrict__ xs, const float* __restrict__ ps,
    float* __restrict__ part) {
  __shared__ float As[32][68];  // ps, d-block
  __shared__ float Bs[32][68];  // relu(xs), e-block
  const int d0 = blockIdx.x * 64;
  const int e0 = blockIdx.y * 64;
  const int kb = blockIdx.z * (KP / KSPLIT);
  const int t  = threadIdx.x;
  const int tx = t & 15, ty = t >> 4;
  float acc[4][4] = {};

  for (int k0 = kb; k0 < kb + KP / KSPLIT; k0 += 32) {
#pragma unroll
    for (int p = 0; p < 2; ++p) {
      const int idx = t + p * 256;
      const int c4  = idx & 15;
      const int row = idx >> 4;
      const float4 av = *(const float4*)(ps + (size_t)(k0 + row) * D + d0 + c4 * 4);
      *(float4*)&As[row][c4 * 4] = av;
      float4 bv = *(const float4*)(xs + (size_t)(k0 + row) * D + e0 + c4 * 4);
      bv.x = fmaxf(bv.x, 0.f); bv.y = fmaxf(bv.y, 0.f);
      bv.z = fmaxf(bv.z, 0.f); bv.w = fmaxf(bv.w, 0.f);
      *(float4*)&Bs[row][c4 * 4] = bv;
    }
    __syncthreads();
#pragma unroll
    for (int kk = 0; kk < 32; ++kk) {
      const float4 a4 = *(const float4*)&As[kk][ty * 4];
      const float4 b4 = *(const float4*)&Bs[kk][tx * 4];
      const float a[4] = {a4.x, a4.y, a4.z, a4.w};
      const float b[4] = {b4.x, b4.y, b4.z, b4.w};
#pragma unroll
      for (int i = 0; i < 4; ++i)
#pragma unroll
        for (int j = 0; j < 4; ++j)
          acc[i][j] = fmaf(a[i], b[j], acc[i][j]);
    }
    __syncthreads();
  }
  float* dst = part + (size_t)blockIdx.z * D * D;
#pragma unroll
  for (int i = 0; i < 4; ++i) {
    float4 v;
    v.x = acc[i][0]; v.y = acc[i][1]; v.z = acc[i][2]; v.w = acc[i][3];
    *(float4*)(dst + (size_t)(d0 + ty * 4 + i) * D + e0 + tx * 4) = v;
  }
}

// theta = -(sum partials); split-3 into bf16 arrays th0,th1,th2 [d][e]
__global__ __launch_bounds__(256) void theta_combine_kernel(
    const float* __restrict__ part, unsigned short* __restrict__ th0,
    unsigned short* __restrict__ th1, unsigned short* __restrict__ th2) {
  const size_t i = (size_t)blockIdx.x * 256 + threadIdx.x;  // float4 index
  float4 s = ((const float4*)part)[i];
#pragma unroll
  for (int z = 1; z < KSPLIT; ++z) {
    const float4 v = ((const float4*)(part + (size_t)z * D * D))[i];
    s.x += v.x; s.y += v.y; s.z += v.z; s.w += v.w;
  }
  const float vv[4] = {-s.x, -s.y, -s.z, -s.w};
  ushort4 h0, h1, h2;
  unsigned short* p0[4] = {&h0.x, &h0.y, &h0.z, &h0.w};
  unsigned short* p1[4] = {&h1.x, &h1.y, &h1.z, &h1.w};
  unsigned short* p2[4] = {&h2.x, &h2.y, &h2.z, &h2.w};
#pragma unroll
  for (int c = 0; c < 4; ++c) {
    const float v = vv[c];
    const unsigned short a0 = f2bf(v);
    const float r1 = v - bf2f(a0);
    const unsigned short a1 = f2bf(r1);
    const float r2 = r1 - bf2f(a1);
    *p0[c] = a0; *p1[c] = a1; *p2[c] = f2bf(r2);
  }
  ((ushort4*)th0)[i] = h0;
  ((ushort4*)th1)[i] = h1;
  ((ushort4*)th2)[i] = h2;
}

__global__ __launch_bounds__(256) void bias_kernel(const float* __restrict__ ps,
                                                   float* __restrict__ bias) {
  __shared__ float part[4][64];
  const int dc = threadIdx.x & 63;
  const int sl = threadIdx.x >> 6;
  const int d  = blockIdx.x * 64 + dc;
  float s = 0.f;
  for (int k = sl * 256; k < sl * 256 + 256; ++k) s += ps[(size_t)k * D + d];
  part[sl][dc] = s;
  __syncthreads();
  if (threadIdx.x < 64) {
    const int c = threadIdx.x;
    bias[blockIdx.x * 64 + c] =
        -(part[0][c] + part[1][c] + part[2][c] + part[3][c]);
  }
}

// out0 = inp; y* = split3(relu(inp)) in [m][e] bf16.
__global__ __launch_bounds__(256) void init_kernel(
    const float* __restrict__ inp, float* __restrict__ out0,
    unsigned short* __restrict__ y0, unsigned short* __restrict__ y1,
    unsigned short* __restrict__ y2) {
  const size_t i = (size_t)blockIdx.x * 256 + threadIdx.x;  // float4 index
  const float4 v = ((const float4*)inp)[i];
  ((float4*)out0)[i] = v;
  const float vv[4] = {fmaxf(v.x, 0.f), fmaxf(v.y, 0.f),
                       fmaxf(v.z, 0.f), fmaxf(v.w, 0.f)};
  ushort4 h0, h1, h2;
  unsigned short* p0[4] = {&h0.x, &h0.y, &h0.z, &h0.w};
  unsigned short* p1[4] = {&h1.x, &h1.y, &h1.z, &h1.w};
  unsigned short* p2[4] = {&h2.x, &h2.y, &h2.z, &h2.w};
#pragma unroll
  for (int c = 0; c < 4; ++c) {
    const unsigned short a0 = f2bf(vv[c]);
    const float r1 = vv[c] - bf2f(a0);
    const unsigned short a1 = f2bf(r1);
    const float r2 = r1 - bf2f(a1);
    *p0[c] = a0; *p1[c] = a1; *p2[c] = f2bf(r2);
  }
  ((ushort4*)y0)[i] = h0;
  ((ushort4*)y1)[i] = h1;
  ((ushort4*)y2)[i] = h2;
}

// ---------------------------------------------------------------------------
// Fallback feval<MODE> (R6 path), kept in case cooperative launch fails.
// ---------------------------------------------------------------------------
template <int MODE>
__global__ __launch_bounds__(256) void feval_kernel(
    const unsigned short* __restrict__ ya0, const unsigned short* __restrict__ ya1,
    const unsigned short* __restrict__ ya2, const unsigned short* __restrict__ th0,
    const unsigned short* __restrict__ th1, const unsigned short* __restrict__ th2,
    const float* __restrict__ bias, const float* __restrict__ bt, int step,
    const float* __restrict__ uStd, float* __restrict__ acc,
    unsigned short* __restrict__ yw0, unsigned short* __restrict__ yw1,
    unsigned short* __restrict__ yw2, float* __restrict__ outStd) {
  __shared__ unsigned short lds[2][2][3][64][32];  // 48 KB
  const int t    = threadIdx.x;
  const int w    = t >> 6;
  const int lane = t & 63;
  const int nl   = lane & 15;
  const int qq   = lane >> 4;
  const int m0   = blockIdx.x * 64;
  const int n0   = blockIdx.y * 64;
  const int msb  = (w & 1) * 32;
  const int nsb  = (w >> 1) * 32;
  const float dt = bt[step + 1] - bt[step];
  const unsigned short* Aarr[3] = {ya0, ya1, ya2};
  const unsigned short* Tarr[3] = {th0, th1, th2};

  auto dma = [&](int buf, int slab) {
    const int e0 = slab * 32;
#pragma unroll
    for (int j = 0; j < 3; ++j) {
      const int cb  = (w * 3 + j) * 64;       // wave-uniform chunk base
      const int s   = cb >> 8;                // wave-uniform split
      const int rem = (cb & 255) + lane;      // stays < 256 (cb % 64 == 0)
      const int r   = rem >> 2;
      const int q   = (rem & 3) ^ (r & 3);
      unsigned short* dA = &lds[buf][0][0][0][0] + (size_t)cb * 8;
      unsigned short* dB = &lds[buf][1][0][0][0] + (size_t)cb * 8;
      glds16(Aarr[s] + (size_t)(m0 + r) * D + e0 + q * 8, dA);
      glds16(Tarr[s] + (size_t)(n0 + r) * D + e0 + q * 8, dB);
    }
  };

  f32x4 C[2][2];
#pragma unroll
  for (int ms = 0; ms < 2; ++ms)
#pragma unroll
    for (int ns = 0; ns < 2; ++ns) C[ms][ns] = (f32x4){0.f, 0.f, 0.f, 0.f};

  dma(0, 0);
  __syncthreads();

  for (int slab = 0; slab < 16; ++slab) {
    const int buf = slab & 1;
    if (slab + 1 < 16) dma(buf ^ 1, slab + 1);
    short8 av[2][3], bv[2][3];
#pragma unroll
    for (int ms = 0; ms < 2; ++ms) {
      const int r   = msb + ms * 16 + nl;
      const int pos = (qq ^ (r & 3)) * 8;
#pragma unroll
      for (int s = 0; s < 3; ++s)
        av[ms][s] = *(const short8*)&lds[buf][0][s][r][pos];
    }
#pragma unroll
    for (int ns = 0; ns < 2; ++ns) {
      const int r   = nsb + ns * 16 + nl;
      const int pos = (qq ^ (r & 3)) * 8;
#pragma unroll
      for (int s = 0; s < 3; ++s)
        bv[ns][s] = *(const short8*)&lds[buf][1][s][r][pos];
    }
#pragma unroll
    for (int ms = 0; ms < 2; ++ms)
#pragma unroll
      for (int ns = 0; ns < 2; ++ns) {
        f32x4 c = C[ms][ns];
        c = __builtin_amdgcn_mfma_f32_16x16x32_bf16(av[ms][0], bv[ns][0], c, 0, 0, 0);
        c = __builtin_amdgcn_mfma_f32_16x16x32_bf16(av[ms][0], bv[ns][1], c, 0, 0, 0);
        c = __builtin_amdgcn_mfma_f32_16x16x32_bf16(av[ms][1], bv[ns][0], c, 0, 0, 0);
        c = __builtin_amdgcn_mfma_f32_16x16x32_bf16(av[ms][0], bv[ns][2], c, 0, 0, 0);
        c = __builtin_amdgcn_mfma_f32_16x16x32_bf16(av[ms][1], bv[ns][1], c, 0, 0, 0);
        c = __builtin_amdgcn_mfma_f32_16x16x32_bf16(av[ms][2], bv[ns][0], c, 0, 0, 0);
        C[ms][ns] = c;
      }
    __syncthreads();
  }

  const float cn = (MODE == 2) ? dt : 0.5f * dt;
  const float s6 = dt * (1.f / 6.f);
#pragma unroll
  for (int ms = 0; ms < 2; ++ms) {
#pragma unroll
    for (int ns = 0; ns < 2; ++ns) {
      const int n = n0 + nsb + ns * 16 + nl;
      const float bb = bias[n];
#pragma unroll
      for (int r = 0; r < 4; ++r) {
        const int m = m0 + msb + ms * 16 + qq * 4 + r;
        const size_t off = (size_t)m * D + n;
        const float kv = C[ms][ns][r] + bb;
        float y;
        if constexpr (MODE == 0) {
          acc[off] = kv;
          y = fmaf(cn, kv, uStd[off]);
        } else if constexpr (MODE <= 2) {
          const float a = acc[off];
          acc[off] = fmaf(2.f, kv, a);
          y = fmaf(cn, kv, uStd[off]);
        } else {
          const float a = acc[off];
          y = fmaf(s6, a + kv, uStd[off]);
          outStd[off] = y;
        }
        const float ry = fmaxf(y, 0.f);
        const unsigned short h0 = f2bf(ry);
        const float r1 = ry - bf2f(h0);
        const unsigned short h1 = f2bf(r1);
        const float r2 = r1 - bf2f(h1);
        yw0[off] = h0;
        yw1[off] = h1;
        yw2[off] = f2bf(r2);
      }
    }
  }
}

// ---------------------------------------------------------------------------
// Fused cooperative kernel: all 5 RK4 steps x 4 stages. u and the RK4
// accumulator live in registers; ya<->yb ping-pong per stage with a grid
// sync between stages. Grid (64,8)=512 blocks = exactly 2/CU at 48 KB LDS;
// __launch_bounds__(256,2) caps VGPR<=256 so co-residency is guaranteed.
// ---------------------------------------------------------------------------
__global__ __launch_bounds__(256, 2) void fused_rk4_kernel(
    unsigned short* ya0, unsigned short* ya1, unsigned short* ya2,
    unsigned short* yb0, unsigned short* yb1, unsigned short* yb2,
    const unsigned short* th0, const unsigned short* th1,
    const unsigned short* th2, const float* bias, const float* bt,
    float* out) {
  __shared__ unsigned short lds[2][2][3][64][32];  // 48 KB
  const int t    = threadIdx.x;
  const int w    = t >> 6;
  const int lane = t & 63;
  const int nl   = lane & 15;
  const int qq   = lane >> 4;
  const int m0   = blockIdx.x * 64;
  const int n0   = blockIdx.y * 64;
  const int msb  = (w & 1) * 32;
  const int nsb  = (w >> 1) * 32;
  const unsigned short* Tarr[3] = {th0, th1, th2};

  float u[2][2][4];   // register-resident u for this thread's 16 elements
  float a[2][2][4];   // register-resident RK4 accumulator
  float bb[2];
#pragma unroll
  for (int ns = 0; ns < 2; ++ns) bb[ns] = bias[n0 + nsb + ns * 16 + nl];
#pragma unroll
  for (int ms = 0; ms < 2; ++ms)
#pragma unroll
    for (int ns = 0; ns < 2; ++ns)
#pragma unroll
      for (int r = 0; r < 4; ++r) {
        const size_t off = (size_t)(m0 + msb + ms * 16 + qq * 4 + r) * D +
                           (n0 + nsb + ns * 16 + nl);
        u[ms][ns][r] = out[off];  // out[0] = inp (written by init_kernel)
        a[ms][ns][r] = 0.f;
      }

  cg::grid_group grid = cg::this_grid();

#pragma unroll 1
  for (int g = 0; g < 20; ++g) {
    const int s = g >> 2;
    const int j = g & 3;
    const float dt = bt[s + 1] - bt[s];
    // strict ping-pong: even g reads ya, writes yb; odd g the reverse.
    const unsigned short* Aarr[3];
    unsigned short* W0;
    unsigned short* W1;
    unsigned short* W2;
    if ((g & 1) == 0) {
      Aarr[0] = ya0; Aarr[1] = ya1; Aarr[2] = ya2;
      W0 = yb0; W1 = yb1; W2 = yb2;
    } else {
      Aarr[0] = yb0; Aarr[1] = yb1; Aarr[2] = yb2;
      W0 = ya0; W1 = ya1; W2 = ya2;
    }

    auto dma = [&](int buf, int slab) {
      const int e0 = slab * 32;
#pragma unroll
      for (int jj = 0; jj < 3; ++jj) {
        const int cb  = (w * 3 + jj) * 64;      // wave-uniform chunk base
        const int sp  = cb >> 8;                // wave-uniform split
        const int rem = (cb & 255) + lane;      // stays < 256
        const int r   = rem >> 2;
        const int q   = (rem & 3) ^ (r & 3);
        unsigned short* dA = &lds[buf][0][0][0][0] + (size_t)cb * 8;
        unsigned short* dB = &lds[buf][1][0][0][0] + (size_t)cb * 8;
        glds16(Aarr[sp] + (size_t)(m0 + r) * D + e0 + q * 8, dA);
        glds16(Tarr[sp] + (size_t)(n0 + r) * D + e0 + q * 8, dB);
      }
    };

    f32x4 C[2][2];
#pragma unroll
    for (int ms = 0; ms < 2; ++ms)
#pragma unroll
      for (int ns = 0; ns < 2; ++ns) C[ms][ns] = (f32x4){0.f, 0.f, 0.f, 0.f};

    dma(0, 0);
    __syncthreads();

    for (int slab = 0; slab < 16; ++slab) {
      const int buf = slab & 1;
      if (slab + 1 < 16) dma(buf ^ 1, slab + 1);
      short8 av[2][3], bv[2][3];
#pragma unroll
      for (int ms = 0; ms < 2; ++ms) {
        const int r   = msb + ms * 16 + nl;
        const int pos = (qq ^ (r & 3)) * 8;
#pragma unroll
        for (int sp = 0; sp < 3; ++sp)
          av[ms][sp] = *(const short8*)&lds[buf][0][sp][r][pos];
      }
#pragma unroll
      for (int ns = 0; ns < 2; ++ns) {
        const int r   = nsb + ns * 16 + nl;
        const int pos = (qq ^ (r & 3)) * 8;
#pragma unroll
        for (int sp = 0; sp < 3; ++sp)
          bv[ns][sp] = *(const short8*)&lds[buf][1][sp][r][pos];
      }
#pragma unroll
      for (int ms = 0; ms < 2; ++ms)
#pragma unroll
        for (int ns = 0; ns < 2; ++ns) {
          f32x4 c = C[ms][ns];
          c = __builtin_amdgcn_mfma_f32_16x16x32_bf16(av[ms][0], bv[ns][0], c, 0, 0, 0);
          c = __builtin_amdgcn_mfma_f32_16x16x32_bf16(av[ms][0], bv[ns][1], c, 0, 0, 0);
          c = __builtin_amdgcn_mfma_f32_16x16x32_bf16(av[ms][1], bv[ns][0], c, 0, 0, 0);
          c = __builtin_amdgcn_mfma_f32_16x16x32_bf16(av[ms][0], bv[ns][2], c, 0, 0, 0);
          c = __builtin_amdgcn_mfma_f32_16x16x32_bf16(av[ms][1], bv[ns][1], c, 0, 0, 0);
          c = __builtin_amdgcn_mfma_f32_16x16x32_bf16(av[ms][2], bv[ns][0], c, 0, 0, 0);
          C[ms][ns] = c;
        }
      __syncthreads();
    }

    // ---- epilogue: RK4 state update entirely in registers ----------------
    const float cn = (j == 2) ? dt : 0.5f * dt;
    const float s6 = dt * (1.f / 6.f);
    const bool last = (g == 19);
#pragma unroll
    for (int ms = 0; ms < 2; ++ms)
#pragma unroll
      for (int ns = 0; ns < 2; ++ns)
#pragma unroll
        for (int r = 0; r < 4; ++r) {
          const size_t off = (size_t)(m0 + msb + ms * 16 + qq * 4 + r) * D +
                             (n0 + nsb + ns * 16 + nl);
          const float kv = C[ms][ns][r] + bb[ns];
          float y;
          if (j == 0) {
            a[ms][ns][r] = kv;
            y = fmaf(cn, kv, u[ms][ns][r]);
          } else if (j != 3) {
            a[ms][ns][r] = fmaf(2.f, kv, a[ms][ns][r]);
            y = fmaf(cn, kv, u[ms][ns][r]);
          } else {
            y = fmaf(s6, a[ms][ns][r] + kv, u[ms][ns][r]);
            u[ms][ns][r] = y;
            out[(size_t)(s + 1) * M * D + off] = y;
          }
          if (!last) {
            const float ry = fmaxf(y, 0.f);
            const unsigned short h0 = f2bf(ry);
            const float r1 = ry - bf2f(h0);
            const unsigned short h1 = f2bf(r1);
            const float r2 = r1 - bf2f(h1);
            W0[off] = h0;
            W1[off] = h1;
            W2[off] = f2bf(r2);
          }
        }

    if (!last) {
      __threadfence();  // make yw* visible device-wide before grid barrier
      grid.sync();
    }
  }
}

}  // namespace

extern "C" void kernel_launch(void* const* d_in, const int* in_sizes, int n_in,
                              void* d_out, int out_size, void* d_ws, size_t ws_size,
                              hipStream_t stream) {
  (void)in_sizes; (void)n_in; (void)out_size; (void)ws_size;
  const float* xs  = (const float*)d_in[0];  // x_params (K,1,D)
  const float* ps  = (const float*)d_in[1];  // p_params (K,1,D)
  // d_in[2] Mbar, d_in[3] Mbar_b: identity -> inv() no-op
  const float* inp = (const float*)d_in[4];  // (M,1,D)
  const float* btH = (const float*)d_in[5];  // (T,)
  float* out = (float*)d_out;                // (T, M, 1, D)
  float* ws  = (float*)d_ws;

  float* acc  = ws;                          // M*D floats (8 MB)
  float* bias = acc + (size_t)M * D;         // 512
  unsigned short* th0 = (unsigned short*)(bias + 512);   // D*D bf16 each
  unsigned short* th1 = th0 + (size_t)D * D;
  unsigned short* th2 = th1 + (size_t)D * D;
  unsigned short* ya0 = th2 + (size_t)D * D;             // M*D bf16 each
  unsigned short* ya1 = ya0 + (size_t)M * D;
  unsigned short* ya2 = ya1 + (size_t)M * D;
  unsigned short* yb0 = ya2 + (size_t)M * D;
  unsigned short* yb1 = yb0 + (size_t)M * D;
  unsigned short* yb2 = yb1 + (size_t)M * D;             // total ~34 MB
  float* part = acc;  // theta partials: KSPLIT*D*D = M*D floats exactly

  theta_partial_kernel<<<dim3(8, 8, KSPLIT), 256, 0, stream>>>(xs, ps, part);
  theta_combine_kernel<<<(D * D) / (4 * 256), 256, 0, stream>>>(part, th0, th1, th2);
  bias_kernel<<<D / 64, 256, 0, stream>>>(ps, bias);
  init_kernel<<<(M * D) / (4 * 256), 256, 0, stream>>>(inp, out, ya0, ya1, ya2);

  const dim3 grid(M / 64, D / 64);  // (64, 8) = 512 blocks = 2/CU exactly

  void* kargs[12];
  kargs[0]  = (void*)&ya0;
  kargs[1]  = (void*)&ya1;
  kargs[2]  = (void*)&ya2;
  kargs[3]  = (void*)&yb0;
  kargs[4]  = (void*)&yb1;
  kargs[5]  = (void*)&yb2;
  kargs[6]  = (void*)&th0;
  kargs[7]  = (void*)&th1;
  kargs[8]  = (void*)&th2;
  kargs[9]  = (void*)&bias;
  kargs[10] = (void*)&btH;
  kargs[11] = (void*)&out;

  const hipError_t e = hipLaunchCooperativeKernel(
      (const void*)fused_rk4_kernel, grid, dim3(256), kargs, 0, stream);

  if (e != hipSuccess) {
    // Fallback: proven R6 20-launch path (acc/u round-trip through global).
    for (int s = 0; s < 5; ++s) {
      float* u     = out + (size_t)s * M * D;
      float* unext = out + (size_t)(s + 1) * M * D;
      feval_kernel<0><<<grid, 256, 0, stream>>>(ya0, ya1, ya2, th0, th1, th2, bias,
                                                btH, s, u, acc, yb0, yb1, yb2, nullptr);
      feval_kernel<1><<<grid, 256, 0, stream>>>(yb0, yb1, yb2, th0, th1, th2, bias,
                                                btH, s, u, acc, ya0, ya1, ya2, nullptr);
      feval_kernel<2><<<grid, 256, 0, stream>>>(ya0, ya1, ya2, th0, th1, th2, bias,
                                                btH, s, u, acc, yb0, yb1, yb2, nullptr);
      feval_kernel<3><<<grid, 256, 0, stream>>>(yb0, yb1, yb2, th0, th1, th2, bias,
                                                btH, s, u, acc, ya0, ya1, ya2, unext);
    }
  }
}

// Round 2
// 819.036 us; speedup vs baseline: 3.2931x; 3.2931x over previous
//
#include <hip/hip_runtime.h>

// ShootingBlock: only the u-trajectory is observable (traj records y[2K:];
// du = relu(u)@theta^T + bias is self-contained; Mbar/Mbar_b are identity).
//
// R8 (post-mortem of R7): grid.sync() costs ~110us/sync on gfx950 -> fusion
// reverted; back to 20 launches. New feval structure:
//   * ONE WAVE per 64x64 tile (64-thr blocks, 512 blocks = 2/CU). A single
//     wave reads each staged LDS byte exactly once (old 4-wave block read
//     everything twice), and NO __syncthreads exists -> no vmcnt(0)+lgkm(0)
//     barrier drain per slab.
//   * Fragment-major LDS: each 1KB chunk = one (arr,split,rowgroup) MFMA
//     fragment in lane order. Reads are ds_read_b128 at base+lane*16 --
//     contiguous 1KB per wave = zero bank conflicts (R6 layout measured
//     1.55e6 conflict-cycles/feval: rows r and r+4 aliased 8-way).
//     DMA side: global_load_lds writes base+lane*16 linearly; the per-lane
//     GLOBAL source is permuted so fragments land in lane order.
//   * Triple-buffered (72KB LDS), distance-2 prefetch, counted
//     s_waitcnt vmcnt(48/24/0) + sched_barrier(0). vmcnt(0) drain before
//     the first DMA makes load counting exact.
// Numerics identical to R6: split-3 bf16, same 6 products, same order.

namespace {

constexpr int KP = 1024;
constexpr int D  = 512;
constexpr int M  = 4096;

typedef __attribute__((ext_vector_type(8))) short short8;   // 8 bf16 (4 VGPRs)
typedef __attribute__((ext_vector_type(4))) float f32x4;

__device__ __forceinline__ unsigned short f2bf(float f) {  // RNE
  unsigned int u = __float_as_uint(f);
  u += 0x7FFF + ((u >> 16) & 1);
  return (unsigned short)(u >> 16);
}
__device__ __forceinline__ float bf2f(unsigned short h) {
  return __uint_as_float(((unsigned int)h) << 16);
}

__device__ __forceinline__ void glds16(const unsigned short* g, unsigned short* l) {
  __builtin_amdgcn_global_load_lds(
      (__attribute__((address_space(1))) const void*)g,
      (__attribute__((address_space(3))) void*)l, 16, 0, 0);
}

// ---------------------------------------------------------------------------
// part[z][d][e] = sum_{k in chunk z} ps[k][d] * relu(xs[k][e])   (std layout)
// ---------------------------------------------------------------------------
constexpr int KSPLIT = 8;

__global__ __launch_bounds__(256) void theta_partial_kernel(
    const float* __restrict__ xs, const float* __restrict__ ps,
    float* __restrict__ part) {
  __shared__ float As[32][68];  // ps, d-block
  __shared__ float Bs[32][68];  // relu(xs), e-block
  const int d0 = blockIdx.x * 64;
  const int e0 = blockIdx.y * 64;
  const int kb = blockIdx.z * (KP / KSPLIT);
  const int t  = threadIdx.x;
  const int tx = t & 15, ty = t >> 4;
  float acc[4][4] = {};

  for (int k0 = kb; k0 < kb + KP / KSPLIT; k0 += 32) {
#pragma unroll
    for (int p = 0; p < 2; ++p) {
      const int idx = t + p * 256;
      const int c4  = idx & 15;
      const int row = idx >> 4;
      const float4 av = *(const float4*)(ps + (size_t)(k0 + row) * D + d0 + c4 * 4);
      *(float4*)&As[row][c4 * 4] = av;
      float4 bv = *(const float4*)(xs + (size_t)(k0 + row) * D + e0 + c4 * 4);
      bv.x = fmaxf(bv.x, 0.f); bv.y = fmaxf(bv.y, 0.f);
      bv.z = fmaxf(bv.z, 0.f); bv.w = fmaxf(bv.w, 0.f);
      *(float4*)&Bs[row][c4 * 4] = bv;
    }
    __syncthreads();
#pragma unroll
    for (int kk = 0; kk < 32; ++kk) {
      const float4 a4 = *(const float4*)&As[kk][ty * 4];
      const float4 b4 = *(const float4*)&Bs[kk][tx * 4];
      const float a[4] = {a4.x, a4.y, a4.z, a4.w};
      const float b[4] = {b4.x, b4.y, b4.z, b4.w};
#pragma unroll
      for (int i = 0; i < 4; ++i)
#pragma unroll
        for (int j = 0; j < 4; ++j)
          acc[i][j] = fmaf(a[i], b[j], acc[i][j]);
    }
    __syncthreads();
  }
  float* dst = part + (size_t)blockIdx.z * D * D;
#pragma unroll
  for (int i = 0; i < 4; ++i) {
    float4 v;
    v.x = acc[i][0]; v.y = acc[i][1]; v.z = acc[i][2]; v.w = acc[i][3];
    *(float4*)(dst + (size_t)(d0 + ty * 4 + i) * D + e0 + tx * 4) = v;
  }
}

// theta = -(sum partials); split-3 into bf16 arrays th0,th1,th2 [d][e]
__global__ __launch_bounds__(256) void theta_combine_kernel(
    const float* __restrict__ part, unsigned short* __restrict__ th0,
    unsigned short* __restrict__ th1, unsigned short* __restrict__ th2) {
  const size_t i = (size_t)blockIdx.x * 256 + threadIdx.x;  // float4 index
  float4 s = ((const float4*)part)[i];
#pragma unroll
  for (int z = 1; z < KSPLIT; ++z) {
    const float4 v = ((const float4*)(part + (size_t)z * D * D))[i];
    s.x += v.x; s.y += v.y; s.z += v.z; s.w += v.w;
  }
  const float vv[4] = {-s.x, -s.y, -s.z, -s.w};
  ushort4 h0, h1, h2;
  unsigned short* p0[4] = {&h0.x, &h0.y, &h0.z, &h0.w};
  unsigned short* p1[4] = {&h1.x, &h1.y, &h1.z, &h1.w};
  unsigned short* p2[4] = {&h2.x, &h2.y, &h2.z, &h2.w};
#pragma unroll
  for (int c = 0; c < 4; ++c) {
    const float v = vv[c];
    const unsigned short a0 = f2bf(v);
    const float r1 = v - bf2f(a0);
    const unsigned short a1 = f2bf(r1);
    const float r2 = r1 - bf2f(a1);
    *p0[c] = a0; *p1[c] = a1; *p2[c] = f2bf(r2);
  }
  ((ushort4*)th0)[i] = h0;
  ((ushort4*)th1)[i] = h1;
  ((ushort4*)th2)[i] = h2;
}

__global__ __launch_bounds__(256) void bias_kernel(const float* __restrict__ ps,
                                                   float* __restrict__ bias) {
  __shared__ float part[4][64];
  const int dc = threadIdx.x & 63;
  const int sl = threadIdx.x >> 6;
  const int d  = blockIdx.x * 64 + dc;
  float s = 0.f;
  for (int k = sl * 256; k < sl * 256 + 256; ++k) s += ps[(size_t)k * D + d];
  part[sl][dc] = s;
  __syncthreads();
  if (threadIdx.x < 64) {
    const int c = threadIdx.x;
    bias[blockIdx.x * 64 + c] =
        -(part[0][c] + part[1][c] + part[2][c] + part[3][c]);
  }
}

// out0 = inp; y* = split3(relu(inp)) in [m][e] bf16.
__global__ __launch_bounds__(256) void init_kernel(
    const float* __restrict__ inp, float* __restrict__ out0,
    unsigned short* __restrict__ y0, unsigned short* __restrict__ y1,
    unsigned short* __restrict__ y2) {
  const size_t i = (size_t)blockIdx.x * 256 + threadIdx.x;  // float4 index
  const float4 v = ((const float4*)inp)[i];
  ((float4*)out0)[i] = v;
  const float vv[4] = {fmaxf(v.x, 0.f), fmaxf(v.y, 0.f),
                       fmaxf(v.z, 0.f), fmaxf(v.w, 0.f)};
  ushort4 h0, h1, h2;
  unsigned short* p0[4] = {&h0.x, &h0.y, &h0.z, &h0.w};
  unsigned short* p1[4] = {&h1.x, &h1.y, &h1.z, &h1.w};
  unsigned short* p2[4] = {&h2.x, &h2.y, &h2.z, &h2.w};
#pragma unroll
  for (int c = 0; c < 4; ++c) {
    const unsigned short a0 = f2bf(vv[c]);
    const float r1 = vv[c] - bf2f(a0);
    const unsigned short a1 = f2bf(r1);
    const float r2 = r1 - bf2f(a1);
    *p0[c] = a0; *p1[c] = a1; *p2[c] = f2bf(r2);
  }
  ((ushort4*)y0)[i] = h0;
  ((ushort4*)y1)[i] = h1;
  ((ushort4*)y2)[i] = h2;
}

// ---------------------------------------------------------------------------
// feval<MODE>: k[m][n] = bias[n] + sum_e A[m][e]*theta[n][e], A = split yin.
//  MODE 0: acc = k;   y = u + dt/2 k     MODE 1: acc += 2k;  y = u + dt/2 k
//  MODE 2: acc += 2k; y = u + dt   k     MODE 3: y = u + dt/6 (acc+k) -> out
//
// One wave per 64x64 tile. LDS lds[3][24][512]: chunk c = (arr*3+s)*4+rg is
// one MFMA fragment (16 rows x 8 k) in LANE ORDER: position p holds
// row (rg*16 + (p&15)), k-chunk (p>>4). DMA writes base+lane*16 linearly
// with the global source permuted to match; reads are contiguous 1KB.
// Triple-buffered, prefetch distance 2, counted vmcnt (24 loads per slab).
// ---------------------------------------------------------------------------
template <int MODE>
__global__ __launch_bounds__(64) void feval_kernel(
    const unsigned short* __restrict__ ya0, const unsigned short* __restrict__ ya1,
    const unsigned short* __restrict__ ya2, const unsigned short* __restrict__ th0,
    const unsigned short* __restrict__ th1, const unsigned short* __restrict__ th2,
    const float* __restrict__ bias, const float* __restrict__ bt, int step,
    const float* __restrict__ uStd, float* __restrict__ acc,
    unsigned short* __restrict__ yw0, unsigned short* __restrict__ yw1,
    unsigned short* __restrict__ yw2, float* __restrict__ outStd) {
  __shared__ unsigned short lds[3][24][512];  // 72 KB, 1KB fragment chunks
  const int lane = threadIdx.x;               // single wave of 64
  const int nl   = lane & 15;
  const int qq   = lane >> 4;
  const int m0   = blockIdx.x * 64;
  const int n0   = blockIdx.y * 64;
  const float dt = bt[step + 1] - bt[step];

  float bb[4];
#pragma unroll
  for (int ns = 0; ns < 4; ++ns) bb[ns] = bias[n0 + ns * 16 + nl];

  // Per-lane source bases: P[arr*3+s]; arr 0 = A rows (m0), arr 1 = theta
  // rows (n0). Lane term (nl rows, qq k-chunk) folded in once.
  const unsigned short* P[6];
  P[0] = ya0 + (size_t)(m0 + nl) * D + qq * 8;
  P[1] = ya1 + (size_t)(m0 + nl) * D + qq * 8;
  P[2] = ya2 + (size_t)(m0 + nl) * D + qq * 8;
  P[3] = th0 + (size_t)(n0 + nl) * D + qq * 8;
  P[4] = th1 + (size_t)(n0 + nl) * D + qq * 8;
  P[5] = th2 + (size_t)(n0 + nl) * D + qq * 8;

  auto dma = [&](int buf, int slab) {
    const int e0 = slab * 32;
#pragma unroll
    for (int c = 0; c < 24; ++c) {
      const int ps = c >> 2;  // arr*3+s
      const int rg = c & 3;   // rowgroup
      glds16(P[ps] + (size_t)rg * 16 * D + e0, &lds[buf][c][0]);
    }
  };

  f32x4 C[4][4];
#pragma unroll
  for (int ms = 0; ms < 4; ++ms)
#pragma unroll
    for (int ns = 0; ns < 4; ++ns) C[ms][ns] = (f32x4){0.f, 0.f, 0.f, 0.f};

  // Drain everything so vmcnt counting below is exact (24 loads per dma).
  asm volatile("s_waitcnt vmcnt(0)" ::: "memory");
  dma(0, 0);
  dma(1, 1);

#pragma unroll
  for (int slab = 0; slab < 16; ++slab) {
    const int buf = slab % 3;
    if (slab + 2 < 16) dma((slab + 2) % 3, slab + 2);
    // Wait for this slab's 24 loads; allow the (up to) 2 prefetched slabs
    // (48 loads) to stay in flight. Never drain to 0 mid-loop.
    if (slab < 14) {
      asm volatile("s_waitcnt vmcnt(48)" ::: "memory");
    } else if (slab == 14) {
      asm volatile("s_waitcnt vmcnt(24)" ::: "memory");
    } else {
      asm volatile("s_waitcnt vmcnt(0)" ::: "memory");
    }
    __builtin_amdgcn_sched_barrier(0);

    short8 av[4][3];
#pragma unroll
    for (int g = 0; g < 4; ++g)
#pragma unroll
      for (int s = 0; s < 3; ++s)
        av[g][s] = *(const short8*)&lds[buf][s * 4 + g][lane * 8];

#pragma unroll
    for (int nh = 0; nh < 2; ++nh) {   // B in halves to cap VGPR pressure
      short8 bv[2][3];
#pragma unroll
      for (int g = 0; g < 2; ++g)
#pragma unroll
        for (int s = 0; s < 3; ++s)
          bv[g][s] = *(const short8*)&lds[buf][12 + s * 4 + nh * 2 + g][lane * 8];
#pragma unroll
      for (int ms = 0; ms < 4; ++ms)
#pragma unroll
        for (int g = 0; g < 2; ++g) {
          f32x4 c = C[ms][nh * 2 + g];
          c = __builtin_amdgcn_mfma_f32_16x16x32_bf16(av[ms][0], bv[g][0], c, 0, 0, 0);
          c = __builtin_amdgcn_mfma_f32_16x16x32_bf16(av[ms][0], bv[g][1], c, 0, 0, 0);
          c = __builtin_amdgcn_mfma_f32_16x16x32_bf16(av[ms][1], bv[g][0], c, 0, 0, 0);
          c = __builtin_amdgcn_mfma_f32_16x16x32_bf16(av[ms][0], bv[g][2], c, 0, 0, 0);
          c = __builtin_amdgcn_mfma_f32_16x16x32_bf16(av[ms][1], bv[g][1], c, 0, 0, 0);
          c = __builtin_amdgcn_mfma_f32_16x16x32_bf16(av[ms][2], bv[g][0], c, 0, 0, 0);
          C[ms][nh * 2 + g] = c;
        }
    }
  }

  // ---- epilogue: C/D layout col(n)=lane&15, row(m)=(lane>>4)*4+reg ---------
  const float cn = (MODE == 2) ? dt : 0.5f * dt;
  const float s6 = dt * (1.f / 6.f);
#pragma unroll
  for (int ms = 0; ms < 4; ++ms) {
#pragma unroll
    for (int ns = 0; ns < 4; ++ns) {
      const int n = n0 + ns * 16 + nl;
#pragma unroll
      for (int r = 0; r < 4; ++r) {
        const int m = m0 + ms * 16 + qq * 4 + r;
        const size_t off = (size_t)m * D + n;
        const float kv = C[ms][ns][r] + bb[ns];
        float y;
        if constexpr (MODE == 0) {
          acc[off] = kv;
          y = fmaf(cn, kv, uStd[off]);
        } else if constexpr (MODE <= 2) {
          const float a = acc[off];
          acc[off] = fmaf(2.f, kv, a);
          y = fmaf(cn, kv, uStd[off]);
        } else {
          const float a = acc[off];
          y = fmaf(s6, a + kv, uStd[off]);
          outStd[off] = y;
        }
        const float ry = fmaxf(y, 0.f);
        const unsigned short h0 = f2bf(ry);
        const float r1 = ry - bf2f(h0);
        const unsigned short h1 = f2bf(r1);
        const float r2 = r1 - bf2f(h1);
        yw0[off] = h0;
        yw1[off] = h1;
        yw2[off] = f2bf(r2);
      }
    }
  }
}

}  // namespace

extern "C" void kernel_launch(void* const* d_in, const int* in_sizes, int n_in,
                              void* d_out, int out_size, void* d_ws, size_t ws_size,
                              hipStream_t stream) {
  (void)in_sizes; (void)n_in; (void)out_size; (void)ws_size;
  const float* xs  = (const float*)d_in[0];  // x_params (K,1,D)
  const float* ps  = (const float*)d_in[1];  // p_params (K,1,D)
  // d_in[2] Mbar, d_in[3] Mbar_b: identity -> inv() no-op
  const float* inp = (const float*)d_in[4];  // (M,1,D)
  const float* bt  = (const float*)d_in[5];  // (T,)
  float* out = (float*)d_out;                // (T, M, 1, D)
  float* ws  = (float*)d_ws;

  float* acc  = ws;                          // M*D floats (8 MB)
  float* bias = acc + (size_t)M * D;         // 512
  unsigned short* th0 = (unsigned short*)(bias + 512);   // D*D bf16 each
  unsigned short* th1 = th0 + (size_t)D * D;
  unsigned short* th2 = th1 + (size_t)D * D;
  unsigned short* ya0 = th2 + (size_t)D * D;             // M*D bf16 each
  unsigned short* ya1 = ya0 + (size_t)M * D;
  unsigned short* ya2 = ya1 + (size_t)M * D;
  unsigned short* yb0 = ya2 + (size_t)M * D;
  unsigned short* yb1 = yb0 + (size_t)M * D;
  unsigned short* yb2 = yb1 + (size_t)M * D;             // total ~34 MB
  float* part = acc;  // theta partials: KSPLIT*D*D = M*D floats exactly

  theta_partial_kernel<<<dim3(8, 8, KSPLIT), 256, 0, stream>>>(xs, ps, part);
  theta_combine_kernel<<<(D * D) / (4 * 256), 256, 0, stream>>>(part, th0, th1, th2);
  bias_kernel<<<D / 64, 256, 0, stream>>>(ps, bias);
  init_kernel<<<(M * D) / (4 * 256), 256, 0, stream>>>(inp, out, ya0, ya1, ya2);

  const dim3 grid(M / 64, D / 64);  // (64, 8) = 512 one-wave blocks, 2/CU
  for (int s = 0; s < 5; ++s) {
    float* u     = out + (size_t)s * M * D;
    float* unext = out + (size_t)(s + 1) * M * D;
    feval_kernel<0><<<grid, 64, 0, stream>>>(ya0, ya1, ya2, th0, th1, th2, bias,
                                             bt, s, u, acc, yb0, yb1, yb2, nullptr);
    feval_kernel<1><<<grid, 64, 0, stream>>>(yb0, yb1, yb2, th0, th1, th2, bias,
                                             bt, s, u, acc, ya0, ya1, ya2, nullptr);
    feval_kernel<2><<<grid, 64, 0, stream>>>(ya0, ya1, ya2, th0, th1, th2, bias,
                                             bt, s, u, acc, yb0, yb1, yb2, nullptr);
    feval_kernel<3><<<grid, 64, 0, stream>>>(yb0, yb1, yb2, th0, th1, th2, bias,
                                             bt, s, u, acc, ya0, ya1, ya2, unext);
  }
}

// Round 4
// 801.997 us; speedup vs baseline: 3.3630x; 1.0212x over previous
//
#include <hip/hip_runtime.h>

// ShootingBlock: only the u-trajectory is observable (traj records y[2K:];
// du = relu(u)@theta^T + bias is self-contained; Mbar/Mbar_b are identity).
//
// R10 (post-mortem of R9): R9's first launch was bit-identical to R6
// (absmax matched) but diverged intermittently under graph replay -> race
// in the NEW fragment-major cross-wave B staging. Revert that. This round
// keeps ONLY the orthogonal half of R9:
//   * A (yin) bypasses LDS: direct global->VGPR loads in MFMA fragment
//     layout (A rows are wave-exclusive; same HBM bytes, no LDS round
//     trip), with an explicit distance-1 register prefetch (av_next).
//   * B (theta) staging and reads are BYTE-FOR-BYTE the R6-proven path:
//     quad-swizzled LDS (slot = q ^ (r&3)), 3 glds16/wave/slab, 16 slabs,
//     one __syncthreads per slab, double-buffered.
// vs R6: LDS writes halved, LDS reads halved (B-only), conflicts ~halved.
// Numerics identical to R6: split-3 bf16, same 6 products, same k-order.

namespace {

constexpr int KP = 1024;
constexpr int D  = 512;
constexpr int M  = 4096;

typedef __attribute__((ext_vector_type(8))) short short8;   // 8 bf16 (4 VGPRs)
typedef __attribute__((ext_vector_type(4))) float f32x4;

__device__ __forceinline__ unsigned short f2bf(float f) {  // RNE
  unsigned int u = __float_as_uint(f);
  u += 0x7FFF + ((u >> 16) & 1);
  return (unsigned short)(u >> 16);
}
__device__ __forceinline__ float bf2f(unsigned short h) {
  return __uint_as_float(((unsigned int)h) << 16);
}

__device__ __forceinline__ void glds16(const unsigned short* g, unsigned short* l) {
  __builtin_amdgcn_global_load_lds(
      (__attribute__((address_space(1))) const void*)g,
      (__attribute__((address_space(3))) void*)l, 16, 0, 0);
}

// ---------------------------------------------------------------------------
// part[z][d][e] = sum_{k in chunk z} ps[k][d] * relu(xs[k][e])   (std layout)
// ---------------------------------------------------------------------------
constexpr int KSPLIT = 8;

__global__ __launch_bounds__(256) void theta_partial_kernel(
    const float* __restrict__ xs, const float* __restrict__ ps,
    float* __restrict__ part) {
  __shared__ float As[32][68];  // ps, d-block
  __shared__ float Bs[32][68];  // relu(xs), e-block
  const int d0 = blockIdx.x * 64;
  const int e0 = blockIdx.y * 64;
  const int kb = blockIdx.z * (KP / KSPLIT);
  const int t  = threadIdx.x;
  const int tx = t & 15, ty = t >> 4;
  float acc[4][4] = {};

  for (int k0 = kb; k0 < kb + KP / KSPLIT; k0 += 32) {
#pragma unroll
    for (int p = 0; p < 2; ++p) {
      const int idx = t + p * 256;
      const int c4  = idx & 15;
      const int row = idx >> 4;
      const float4 av = *(const float4*)(ps + (size_t)(k0 + row) * D + d0 + c4 * 4);
      *(float4*)&As[row][c4 * 4] = av;
      float4 bv = *(const float4*)(xs + (size_t)(k0 + row) * D + e0 + c4 * 4);
      bv.x = fmaxf(bv.x, 0.f); bv.y = fmaxf(bv.y, 0.f);
      bv.z = fmaxf(bv.z, 0.f); bv.w = fmaxf(bv.w, 0.f);
      *(float4*)&Bs[row][c4 * 4] = bv;
    }
    __syncthreads();
#pragma unroll
    for (int kk = 0; kk < 32; ++kk) {
      const float4 a4 = *(const float4*)&As[kk][ty * 4];
      const float4 b4 = *(const float4*)&Bs[kk][tx * 4];
      const float a[4] = {a4.x, a4.y, a4.z, a4.w};
      const float b[4] = {b4.x, b4.y, b4.z, b4.w};
#pragma unroll
      for (int i = 0; i < 4; ++i)
#pragma unroll
        for (int j = 0; j < 4; ++j)
          acc[i][j] = fmaf(a[i], b[j], acc[i][j]);
    }
    __syncthreads();
  }
  float* dst = part + (size_t)blockIdx.z * D * D;
#pragma unroll
  for (int i = 0; i < 4; ++i) {
    float4 v;
    v.x = acc[i][0]; v.y = acc[i][1]; v.z = acc[i][2]; v.w = acc[i][3];
    *(float4*)(dst + (size_t)(d0 + ty * 4 + i) * D + e0 + tx * 4) = v;
  }
}

// theta = -(sum partials); split-3 into bf16 arrays th0,th1,th2 [d][e]
__global__ __launch_bounds__(256) void theta_combine_kernel(
    const float* __restrict__ part, unsigned short* __restrict__ th0,
    unsigned short* __restrict__ th1, unsigned short* __restrict__ th2) {
  const size_t i = (size_t)blockIdx.x * 256 + threadIdx.x;  // float4 index
  float4 s = ((const float4*)part)[i];
#pragma unroll
  for (int z = 1; z < KSPLIT; ++z) {
    const float4 v = ((const float4*)(part + (size_t)z * D * D))[i];
    s.x += v.x; s.y += v.y; s.z += v.z; s.w += v.w;
  }
  const float vv[4] = {-s.x, -s.y, -s.z, -s.w};
  ushort4 h0, h1, h2;
  unsigned short* p0[4] = {&h0.x, &h0.y, &h0.z, &h0.w};
  unsigned short* p1[4] = {&h1.x, &h1.y, &h1.z, &h1.w};
  unsigned short* p2[4] = {&h2.x, &h2.y, &h2.z, &h2.w};
#pragma unroll
  for (int c = 0; c < 4; ++c) {
    const float v = vv[c];
    const unsigned short a0 = f2bf(v);
    const float r1 = v - bf2f(a0);
    const unsigned short a1 = f2bf(r1);
    const float r2 = r1 - bf2f(a1);
    *p0[c] = a0; *p1[c] = a1; *p2[c] = f2bf(r2);
  }
  ((ushort4*)th0)[i] = h0;
  ((ushort4*)th1)[i] = h1;
  ((ushort4*)th2)[i] = h2;
}

__global__ __launch_bounds__(256) void bias_kernel(const float* __restrict__ ps,
                                                   float* __restrict__ bias) {
  __shared__ float part[4][64];
  const int dc = threadIdx.x & 63;
  const int sl = threadIdx.x >> 6;
  const int d  = blockIdx.x * 64 + dc;
  float s = 0.f;
  for (int k = sl * 256; k < sl * 256 + 256; ++k) s += ps[(size_t)k * D + d];
  part[sl][dc] = s;
  __syncthreads();
  if (threadIdx.x < 64) {
    const int c = threadIdx.x;
    bias[blockIdx.x * 64 + c] =
        -(part[0][c] + part[1][c] + part[2][c] + part[3][c]);
  }
}

// out0 = inp; y* = split3(relu(inp)) in [m][e] bf16.
__global__ __launch_bounds__(256) void init_kernel(
    const float* __restrict__ inp, float* __restrict__ out0,
    unsigned short* __restrict__ y0, unsigned short* __restrict__ y1,
    unsigned short* __restrict__ y2) {
  const size_t i = (size_t)blockIdx.x * 256 + threadIdx.x;  // float4 index
  const float4 v = ((const float4*)inp)[i];
  ((float4*)out0)[i] = v;
  const float vv[4] = {fmaxf(v.x, 0.f), fmaxf(v.y, 0.f),
                       fmaxf(v.z, 0.f), fmaxf(v.w, 0.f)};
  ushort4 h0, h1, h2;
  unsigned short* p0[4] = {&h0.x, &h0.y, &h0.z, &h0.w};
  unsigned short* p1[4] = {&h1.x, &h1.y, &h1.z, &h1.w};
  unsigned short* p2[4] = {&h2.x, &h2.y, &h2.z, &h2.w};
#pragma unroll
  for (int c = 0; c < 4; ++c) {
    const unsigned short a0 = f2bf(vv[c]);
    const float r1 = vv[c] - bf2f(a0);
    const unsigned short a1 = f2bf(r1);
    const float r2 = r1 - bf2f(a1);
    *p0[c] = a0; *p1[c] = a1; *p2[c] = f2bf(r2);
  }
  ((ushort4*)y0)[i] = h0;
  ((ushort4*)y1)[i] = h1;
  ((ushort4*)y2)[i] = h2;
}

// ---------------------------------------------------------------------------
// feval<MODE>: k[m][n] = bias[n] + sum_e A[m][e]*theta[n][e], A = split yin.
//  MODE 0: acc = k;   y = u + dt/2 k     MODE 1: acc += 2k;  y = u + dt/2 k
//  MODE 2: acc += 2k; y = u + dt   k     MODE 3: y = u + dt/6 (acc+k) -> out
//
// 64x64 tile, 256 thr = 4 waves, wave w -> 32x32 subtile (msb=(w&1)*32,
// nsb=(w>>1)*32), 2x2 C-frags of 16x16x32.
// A: direct global->VGPR fragment loads (row = m0+msb+ms*16+nl,
//    k = e0 + qq*8), distance-1 register prefetch (av_next).
// B: R6-proven LDS path, verbatim: lds[buf][s][64][32], quad slot
//    XOR-swizzled (slot = q ^ (r&3)), 3 glds16/wave/slab, double-buffered,
//    one __syncthreads per slab.
// ---------------------------------------------------------------------------
template <int MODE>
__global__ __launch_bounds__(256) void feval_kernel(
    const unsigned short* __restrict__ ya0, const unsigned short* __restrict__ ya1,
    const unsigned short* __restrict__ ya2, const unsigned short* __restrict__ th0,
    const unsigned short* __restrict__ th1, const unsigned short* __restrict__ th2,
    const float* __restrict__ bias, const float* __restrict__ bt, int step,
    const float* __restrict__ uStd, float* __restrict__ acc,
    unsigned short* __restrict__ yw0, unsigned short* __restrict__ yw1,
    unsigned short* __restrict__ yw2, float* __restrict__ outStd) {
  __shared__ unsigned short lds[2][3][64][32];  // 24 KB: B (theta) only
  const int t    = threadIdx.x;
  const int w    = t >> 6;
  const int lane = t & 63;
  const int nl   = lane & 15;
  const int qq   = lane >> 4;
  const int m0   = blockIdx.x * 64;
  const int n0   = blockIdx.y * 64;
  const int msb  = (w & 1) * 32;
  const int nsb  = (w >> 1) * 32;
  const float dt = bt[step + 1] - bt[step];
  const unsigned short* Aarr[3] = {ya0, ya1, ya2};
  const unsigned short* Tarr[3] = {th0, th1, th2};

  // Per-lane A fragment row bases: row = m0+msb+ms*16+nl, k offset qq*8.
  const unsigned short* arow[2][3];
#pragma unroll
  for (int ms = 0; ms < 2; ++ms)
#pragma unroll
    for (int s = 0; s < 3; ++s)
      arow[ms][s] = Aarr[s] + (size_t)(m0 + msb + ms * 16 + nl) * D + qq * 8;

  // B staging: verbatim R6 addressing (B half). chunk c (16B units) covers
  // (split s = c>>8, row r = (c&255)>>2, slot qs = c&3); slot holds global
  // quad q = qs ^ (r&3).
  auto dma = [&](int buf, int slab) {
    const int e0 = slab * 32;
#pragma unroll
    for (int j = 0; j < 3; ++j) {
      const int cb  = (w * 3 + j) * 64;       // wave-uniform chunk base
      const int s   = cb >> 8;                // wave-uniform split
      const int rem = (cb & 255) + lane;      // stays < 256 (cb % 64 == 0)
      const int r   = rem >> 2;
      const int q   = (rem & 3) ^ (r & 3);
      unsigned short* dB = &lds[buf][0][0][0] + (size_t)cb * 8;
      glds16(Tarr[s] + (size_t)(n0 + r) * D + e0 + q * 8, dB);
    }
  };

  float bb[2];
#pragma unroll
  for (int ns = 0; ns < 2; ++ns) bb[ns] = bias[n0 + nsb + ns * 16 + nl];

  f32x4 C[2][2];
#pragma unroll
  for (int ms = 0; ms < 2; ++ms)
#pragma unroll
    for (int ns = 0; ns < 2; ++ns) C[ms][ns] = (f32x4){0.f, 0.f, 0.f, 0.f};

  dma(0, 0);

  // A prefetch for slab 0 (plain VGPR loads; no sync surface).
  short8 av_cur[2][3], av_next[2][3];
#pragma unroll
  for (int ms = 0; ms < 2; ++ms)
#pragma unroll
    for (int s = 0; s < 3; ++s)
      av_cur[ms][s] = *(const short8*)(arow[ms][s] + 0);

  __syncthreads();

  for (int slab = 0; slab < 16; ++slab) {
    const int buf = slab & 1;
    if (slab + 1 < 16) dma(buf ^ 1, slab + 1);

    // Prefetch next slab's A fragments (slab 15: redundant reload of 15).
    const int pe0 = (slab + 1 < 16) ? (slab + 1) * 32 : slab * 32;
#pragma unroll
    for (int ms = 0; ms < 2; ++ms)
#pragma unroll
      for (int s = 0; s < 3; ++s)
        av_next[ms][s] = *(const short8*)(arow[ms][s] + pe0);

    short8 bv[2][3];
#pragma unroll
    for (int ns = 0; ns < 2; ++ns) {
      const int r   = nsb + ns * 16 + nl;
      const int pos = (qq ^ (r & 3)) * 8;
#pragma unroll
      for (int s = 0; s < 3; ++s)
        bv[ns][s] = *(const short8*)&lds[buf][s][r][pos];
    }
#pragma unroll
    for (int ms = 0; ms < 2; ++ms)
#pragma unroll
      for (int ns = 0; ns < 2; ++ns) {
        f32x4 c = C[ms][ns];
        c = __builtin_amdgcn_mfma_f32_16x16x32_bf16(av_cur[ms][0], bv[ns][0], c, 0, 0, 0);
        c = __builtin_amdgcn_mfma_f32_16x16x32_bf16(av_cur[ms][0], bv[ns][1], c, 0, 0, 0);
        c = __builtin_amdgcn_mfma_f32_16x16x32_bf16(av_cur[ms][1], bv[ns][0], c, 0, 0, 0);
        c = __builtin_amdgcn_mfma_f32_16x16x32_bf16(av_cur[ms][0], bv[ns][2], c, 0, 0, 0);
        c = __builtin_amdgcn_mfma_f32_16x16x32_bf16(av_cur[ms][1], bv[ns][1], c, 0, 0, 0);
        c = __builtin_amdgcn_mfma_f32_16x16x32_bf16(av_cur[ms][2], bv[ns][0], c, 0, 0, 0);
        C[ms][ns] = c;
      }
#pragma unroll
    for (int ms = 0; ms < 2; ++ms)
#pragma unroll
      for (int s = 0; s < 3; ++s)
        av_cur[ms][s] = av_next[ms][s];
    __syncthreads();
  }

  // ---- epilogue: C/D layout col(n)=lane&15, row(m)=(lane>>4)*4+reg ---------
  const float cn = (MODE == 2) ? dt : 0.5f * dt;
  const float s6 = dt * (1.f / 6.f);
#pragma unroll
  for (int ms = 0; ms < 2; ++ms) {
#pragma unroll
    for (int ns = 0; ns < 2; ++ns) {
      const int n = n0 + nsb + ns * 16 + nl;
#pragma unroll
      for (int r = 0; r < 4; ++r) {
        const int m = m0 + msb + ms * 16 + qq * 4 + r;
        const size_t off = (size_t)m * D + n;
        const float kv = C[ms][ns][r] + bb[ns];
        float y;
        if constexpr (MODE == 0) {
          acc[off] = kv;
          y = fmaf(cn, kv, uStd[off]);
        } else if constexpr (MODE <= 2) {
          const float a = acc[off];
          acc[off] = fmaf(2.f, kv, a);
          y = fmaf(cn, kv, uStd[off]);
        } else {
          const float a = acc[off];
          y = fmaf(s6, a + kv, uStd[off]);
          outStd[off] = y;
        }
        const float ry = fmaxf(y, 0.f);
        const unsigned short h0 = f2bf(ry);
        const float r1 = ry - bf2f(h0);
        const unsigned short h1 = f2bf(r1);
        const float r2 = r1 - bf2f(h1);
        yw0[off] = h0;
        yw1[off] = h1;
        yw2[off] = f2bf(r2);
      }
    }
  }
}

}  // namespace

extern "C" void kernel_launch(void* const* d_in, const int* in_sizes, int n_in,
                              void* d_out, int out_size, void* d_ws, size_t ws_size,
                              hipStream_t stream) {
  (void)in_sizes; (void)n_in; (void)out_size; (void)ws_size;
  const float* xs  = (const float*)d_in[0];  // x_params (K,1,D)
  const float* ps  = (const float*)d_in[1];  // p_params (K,1,D)
  // d_in[2] Mbar, d_in[3] Mbar_b: identity -> inv() no-op
  const float* inp = (const float*)d_in[4];  // (M,1,D)
  const float* bt  = (const float*)d_in[5];  // (T,)
  float* out = (float*)d_out;                // (T, M, 1, D)
  float* ws  = (float*)d_ws;

  float* acc  = ws;                          // M*D floats (8 MB)
  float* bias = acc + (size_t)M * D;         // 512
  unsigned short* th0 = (unsigned short*)(bias + 512);   // D*D bf16 each
  unsigned short* th1 = th0 + (size_t)D * D;
  unsigned short* th2 = th1 + (size_t)D * D;
  unsigned short* ya0 = th2 + (size_t)D * D;             // M*D bf16 each
  unsigned short* ya1 = ya0 + (size_t)M * D;
  unsigned short* ya2 = ya1 + (size_t)M * D;
  unsigned short* yb0 = ya2 + (size_t)M * D;
  unsigned short* yb1 = yb0 + (size_t)M * D;
  unsigned short* yb2 = yb1 + (size_t)M * D;             // total ~34 MB
  float* part = acc;  // theta partials: KSPLIT*D*D = M*D floats exactly

  theta_partial_kernel<<<dim3(8, 8, KSPLIT), 256, 0, stream>>>(xs, ps, part);
  theta_combine_kernel<<<(D * D) / (4 * 256), 256, 0, stream>>>(part, th0, th1, th2);
  bias_kernel<<<D / 64, 256, 0, stream>>>(ps, bias);
  init_kernel<<<(M * D) / (4 * 256), 256, 0, stream>>>(inp, out, ya0, ya1, ya2);

  const dim3 grid(M / 64, D / 64);  // (64, 8) = 512 blocks, 2/CU, 2 waves/SIMD
  for (int s = 0; s < 5; ++s) {
    float* u     = out + (size_t)s * M * D;
    float* unext = out + (size_t)(s + 1) * M * D;
    feval_kernel<0><<<grid, 256, 0, stream>>>(ya0, ya1, ya2, th0, th1, th2, bias,
                                              bt, s, u, acc, yb0, yb1, yb2, nullptr);
    feval_kernel<1><<<grid, 256, 0, stream>>>(yb0, yb1, yb2, th0, th1, th2, bias,
                                              bt, s, u, acc, ya0, ya1, ya2, nullptr);
    feval_kernel<2><<<grid, 256, 0, stream>>>(ya0, ya1, ya2, th0, th1, th2, bias,
                                              bt, s, u, acc, yb0, yb1, yb2, nullptr);
    feval_kernel<3><<<grid, 256, 0, stream>>>(yb0, yb1, yb2, th0, th1, th2, bias,
                                              bt, s, u, acc, ya0, ya1, ya2, unext);
  }
}